// Round 9
// baseline (1535.666 us; speedup 1.0000x reference)
//
#include <hip/hip_runtime.h>

typedef __attribute__((ext_vector_type(8))) short bf16x8;
typedef __attribute__((ext_vector_type(4))) float f32x4;

#define L_DIM 24
#define B_DIM 32
#define S_DIM 512
#define H_DIM 1024
#define M_DIM 16384      // B*S
#define K_DIM 24576      // L*H
#define N_REAL 900
#define NP 1024          // padded N

// round-to-nearest-even fp32 -> bf16
__device__ __forceinline__ short f2bf(float f) {
  unsigned u = __builtin_bit_cast(unsigned, f);
  u += 0x7FFFu + ((u >> 16) & 1u);
  return (short)(u >> 16);
}

// does sorted srow[0..511] contain s? 10-step lower_bound (512 needs 10 halvings).
__device__ __forceinline__ bool row_needed(const int* __restrict__ srow, int s) {
  int lo = 0, hi = 512;
#pragma unroll
  for (int it = 0; it < 10; ++it) {
    const int mid = (lo + hi) >> 1;
    const int v = (mid < 512) ? srow[mid] : 0x7fffffff;
    if (v < s) lo = mid + 1; else hi = mid;
  }
  return lo < 512 && srow[lo] == s;
}

// ---- P0: hidden_states fp32 [L][B][S][H] -> A bf16 [M][K], pre-swizzled:
// element (m,k) at k' = (k & ~63) + (((k>>3 & 7) ^ (m & 7)) * 8) + (k & 7).
// Rows never gathered are skipped (their stale contents are never read).
__global__ __launch_bounds__(256)
void conv_a_kernel(const float* __restrict__ hs, const int* __restrict__ starts,
                   unsigned short* __restrict__ a) {
  for (int m = blockIdx.x; m < M_DIM; m += gridDim.x) {
    const int b = m >> 9, s = m & 511;
    if (s == 0 || !row_needed(starts + b * 512, s)) continue;
    const int m7 = m & 7;
    unsigned short* dstRow = a + (size_t)m * K_DIM;
#pragma unroll
    for (int i = 0; i < 12; ++i) {
      const int g = threadIdx.x + i * 256;        // granule (8 elems)
      const int l = g >> 7;
      const int h = (g & 127) * 8;
      const float* src = hs + (((size_t)l * B_DIM + b) * S_DIM + s) * H_DIM + h;
      float4 f0 = *(const float4*)src;
      float4 f1 = *(const float4*)(src + 4);
      bf16x8 p;
      p[0] = f2bf(f0.x); p[1] = f2bf(f0.y); p[2] = f2bf(f0.z); p[3] = f2bf(f0.w);
      p[4] = f2bf(f1.x); p[5] = f2bf(f1.y); p[6] = f2bf(f1.z); p[7] = f2bf(f1.w);
      const int slot = (g & 7) ^ m7;
      *(bf16x8*)(dstRow + (g & ~7) * 8 + slot * 8) = p;
    }
  }
}

// ---- P1: W1 [K][900] -> W1T bf16 [1024][K], zero-padded rows, swizzled (by n&7)
__global__ __launch_bounds__(256)
void prep_w1t_kernel(const float* __restrict__ w1, unsigned short* __restrict__ w1t) {
  __shared__ unsigned short t[64][72];
  const int n0 = blockIdx.x * 64;
  const int k0 = blockIdx.y * 64;
  const int tid = threadIdx.x;
  {
    const int nl = tid & 63;
    const int n = n0 + nl;
#pragma unroll
    for (int p = 0; p < 16; ++p) {
      const int kl = p * 4 + (tid >> 6);
      float v = (n < N_REAL) ? w1[(size_t)(k0 + kl) * N_REAL + n] : 0.f;
      t[nl][kl] = (unsigned short)f2bf(v);
    }
  }
  __syncthreads();
  {
    const int kl = tid & 63;
#pragma unroll
    for (int p = 0; p < 16; ++p) {
      const int nl2 = p * 4 + (tid >> 6);
      const int n = n0 + nl2;
      const int slot = ((kl >> 3) ^ (n & 7)) & 7;
      w1t[(size_t)n * K_DIM + k0 + slot * 8 + (kl & 7)] = t[nl2][kl];
    }
  }
}

// ---- P2: W2T fp32 [40][1024] (transposed, padded) + b1 padded [1024]
__global__ __launch_bounds__(256)
void prep_small_kernel(const float* __restrict__ w2, const float* __restrict__ b1,
                       float* __restrict__ w2t, float* __restrict__ b1p) {
  const int i = blockIdx.x * 256 + threadIdx.x;
  if (i < 40 * NP) {
    const int j = i >> 10, k = i & (NP - 1);
    w2t[i] = (k < N_REAL) ? w2[(size_t)k * 40 + j] : 0.f;
  }
  const int t2 = i - 40 * NP;
  if (t2 >= 0 && t2 < NP)
    b1p[t2] = (t2 < N_REAL) ? b1[t2] : 0.f;
}

// =====================================================================
// G1: h1 = relu(A @ W1T^T + b1). 256x256 tile, BK=64, 4-phase schedule.
// Full-tile lookahead on BOTH operands: during tile t, stage tile t+2
// into the CURRENT buffers — B halves at ph3/ph4 (B reads end at ph2),
// A halves at ph4 (A reads end at ph3). vmcnt(8) at each ph4 drains
// exactly tile t+1 (oldest 8 loads), keeping t+2's 8 in flight:
// every load gets >= 5 phases (~1200cy) of slack > HBM latency.
// SBAR pins the scheduler on BOTH sides of s_barrier (IntrNoMem hoist fix).
// =====================================================================
#define SBAR() do { __builtin_amdgcn_sched_barrier(0); __builtin_amdgcn_s_barrier(); __builtin_amdgcn_sched_barrier(0); } while (0)
#define WAIT_LGKM0() do { asm volatile("s_waitcnt lgkmcnt(0)" ::: "memory"); __builtin_amdgcn_sched_barrier(0); } while (0)
#define VMWAIT(N) do { asm volatile("s_waitcnt vmcnt(" #N ")" ::: "memory"); __builtin_amdgcn_sched_barrier(0); } while (0)

// stage one 128-row half-tile (16 KiB): 2 x global_load_lds per thread
#define STAGE(DSTREG, GBASE, ROWBASE, HALF, TK) do {                                   \
  _Pragma("unroll")                                                                    \
  for (int _i = 0; _i < 2; ++_i) {                                                     \
    const int _ch = wid * 2 + _i;                                                      \
    const int _row = (HALF) * 128 + _ch * 8 + (lane >> 3);                             \
    __builtin_amdgcn_global_load_lds(                                                  \
      (const __attribute__((address_space(1))) void*)((GBASE) +                        \
          (size_t)((ROWBASE) + _row) * K_DIM + (TK) * 64 + (lane & 7) * 8),            \
      (__attribute__((address_space(3))) void*)((DSTREG) + (HALF) * 16384 + _ch * 1024), \
      16, 0, 0);                                                                       \
  }                                                                                    \
} while (0)

#define LDA4(AV, MIBASE, ABUF) do {                                                    \
  _Pragma("unroll")                                                                    \
  for (int _mi = 0; _mi < 4; ++_mi) {                                                  \
    _Pragma("unroll")                                                                  \
    for (int _kk = 0; _kk < 2; ++_kk) {                                                \
      const int _r = wr * 128 + ((MIBASE) + _mi) * 16 + r15;                           \
      AV[_mi][_kk] = *(const bf16x8*)((ABUF) + _r * 128 + (((_kk)*4 + hi4) ^ (_r & 7)) * 16); \
    }                                                                                  \
  }                                                                                    \
} while (0)

#define LDB2(BV, NIBASE, BBUF) do {                                                    \
  _Pragma("unroll")                                                                    \
  for (int _ni = 0; _ni < 2; ++_ni) {                                                  \
    _Pragma("unroll")                                                                  \
    for (int _kk = 0; _kk < 2; ++_kk) {                                                \
      const int _r = wc * 64 + ((NIBASE) + _ni) * 16 + r15;                            \
      BV[_ni][_kk] = *(const bf16x8*)((BBUF) + _r * 128 + (((_kk)*4 + hi4) ^ (_r & 7)) * 16); \
    }                                                                                  \
  }                                                                                    \
} while (0)

#define MFMA_Q(AV, BV, MIBASE, NIBASE) do {                                            \
  _Pragma("unroll")                                                                    \
  for (int _mi = 0; _mi < 4; ++_mi)                                                    \
    _Pragma("unroll")                                                                  \
    for (int _ni = 0; _ni < 2; ++_ni)                                                  \
      _Pragma("unroll")                                                                \
      for (int _kk = 0; _kk < 2; ++_kk)                                                \
        acc[(MIBASE) + _mi][(NIBASE) + _ni] = __builtin_amdgcn_mfma_f32_16x16x32_bf16( \
            AV[_mi][_kk], BV[_ni][_kk], acc[(MIBASE) + _mi][(NIBASE) + _ni], 0, 0, 0); \
} while (0)

// one K-tile = 4 phases. SA/SB: stage A/B of tile T+2 into the CURRENT
// buffers (B at ph3/ph4 after its ph2-end last read; A at ph4 after ph3-end).
#define TILE_BODY(T, AB, BB, SA, SB, WAITSTMT) do {                                    \
  /* ---- phase 1 ---- */                                                              \
  LDA4(av, 0, (AB));                                                                   \
  LDB2(bv0, 0, (BB));                                                                  \
  SBAR();                                                                              \
  WAIT_LGKM0();                                                                        \
  __builtin_amdgcn_s_setprio(1);                                                       \
  MFMA_Q(av, bv0, 0, 0);                                                               \
  __builtin_amdgcn_s_setprio(0);                                                       \
  SBAR();                                                                              \
  /* ---- phase 2 ---- */                                                              \
  LDB2(bv1, 2, (BB));                                                                  \
  SBAR();                                                                              \
  WAIT_LGKM0();                                                                        \
  __builtin_amdgcn_s_setprio(1);                                                       \
  MFMA_Q(av, bv1, 0, 2);                                                               \
  __builtin_amdgcn_s_setprio(0);                                                       \
  SBAR();                                                                              \
  /* ---- phase 3 ---- */                                                              \
  LDA4(av, 4, (AB));                                                                   \
  if (SB) STAGE((BB), w1t, n0, 0, (T) + 2);                                            \
  SBAR();                                                                              \
  WAIT_LGKM0();                                                                        \
  __builtin_amdgcn_s_setprio(1);                                                       \
  MFMA_Q(av, bv1, 4, 2);                                                               \
  __builtin_amdgcn_s_setprio(0);                                                       \
  SBAR();                                                                              \
  /* ---- phase 4 ---- */                                                              \
  if (SB) STAGE((BB), w1t, n0, 1, (T) + 2);                                            \
  if (SA) { STAGE((AB), a, m0, 0, (T) + 2); STAGE((AB), a, m0, 1, (T) + 2); }          \
  SBAR();                                                                              \
  WAIT_LGKM0();                                                                        \
  __builtin_amdgcn_s_setprio(1);                                                       \
  MFMA_Q(av, bv0, 4, 0);                                                               \
  __builtin_amdgcn_s_setprio(0);                                                       \
  WAITSTMT;                                                                            \
  SBAR();                                                                              \
} while (0)

__global__ __launch_bounds__(512, 2)
void gemm1_8ph_kernel(const unsigned short* __restrict__ a,
                      const unsigned short* __restrict__ w1t,
                      const float* __restrict__ b1p,
                      float* __restrict__ h1) {
  extern __shared__ char L[];   // 128 KiB: A0|B0|A1|B1, 32 KiB each
  char* const Ab0 = L;
  char* const Bb0 = L + 32768;
  char* const Ab1 = L + 65536;
  char* const Bb1 = L + 65536 + 32768;

  const int tid = threadIdx.x;
  const int lane = tid & 63;
  const int wid = tid >> 6;          // 0..7
  const int wr = wid >> 2;           // 0..1 (128-row band)
  const int wc = wid & 3;            // 0..3 (64-col band)
  const int r15 = lane & 15;
  const int hi4 = lane >> 4;         // 0..3

  // bijective XCD mapping: xcd = hw&7 owns m-panels [xcd*8, xcd*8+8) x 4 n-blocks
  const int hw = blockIdx.x;
  const int mb = (hw & 7) * 8 + (hw >> 5);
  const int nb = (hw >> 3) & 3;
  const int m0 = mb * 256;
  const int n0 = nb * 256;

  f32x4 acc[8][4] = {};
  bf16x8 av[4][2], bv0[2][2], bv1[2][2];

  // prologue: tiles 0 and 1 fully staged (16 loads); drain tile 0 (oldest 8)
  STAGE(Ab0, a, m0, 0, 0);
  STAGE(Ab0, a, m0, 1, 0);
  STAGE(Bb0, w1t, n0, 0, 0);
  STAGE(Bb0, w1t, n0, 1, 0);
  STAGE(Ab1, a, m0, 0, 1);
  STAGE(Ab1, a, m0, 1, 1);
  STAGE(Bb1, w1t, n0, 0, 1);
  STAGE(Bb1, w1t, n0, 1, 1);
  VMWAIT(8);
  SBAR();

  // main loop: tiles 0..381, each staging tile t+2 into its own buffers
  for (int kt = 0; kt < 191; ++kt) {
    const int t = 2 * kt;
    TILE_BODY(t,     Ab0, Bb0, 1, 1, VMWAIT(8));
    TILE_BODY(t + 1, Ab1, Bb1, 1, 1, VMWAIT(8));
  }
  // tail: tile 382 computes + drains tile 383's loads; tile 383 computes only
  TILE_BODY(382, Ab0, Bb0, 0, 0, VMWAIT(0));
  TILE_BODY(383, Ab1, Bb1, 0, 0, (void)0);

  // epilogue: relu(acc + b1); C/D: col = lane&15, row = (lane>>4)*4 + r
#pragma unroll
  for (int mi = 0; mi < 8; ++mi) {
#pragma unroll
    for (int ni = 0; ni < 4; ++ni) {
      const int n = n0 + wc * 64 + ni * 16 + r15;
      const float bias = b1p[n];
#pragma unroll
      for (int r = 0; r < 4; ++r) {
        const int m = m0 + wr * 128 + mi * 16 + hi4 * 4 + r;
        const float v = acc[mi][ni][r] + bias;
        h1[(size_t)m * NP + n] = v > 0.f ? v : 0.f;
      }
    }
  }
}

// ---- K2: logits = sigmoid(relu(h1 @ W2 + b2) @ W3 + b3), one wave/row,
//          rows never gathered are skipped (bsearch on sorted starts)
__global__ __launch_bounds__(256)
void layer23_kernel(const float* __restrict__ h1, const float* __restrict__ w2t,
                    const float* __restrict__ b2, const float* __restrict__ w3,
                    const float* __restrict__ b3, const int* __restrict__ starts,
                    float* __restrict__ logits) {
  const int wave = (blockIdx.x * 256 + threadIdx.x) >> 6;
  const int lane = threadIdx.x & 63;
  const int s = wave & 511;
  if (s == 0 || !row_needed(starts + (wave >> 9) * 512, s)) return;
  const float* hrow = h1 + (size_t)wave * NP;
  float acc = 0.f;
  if (lane < 40) {
    const float* wrow = w2t + lane * NP;
    for (int k = 0; k < NP; k += 8) {
      float4 h0 = *(const float4*)(hrow + k);
      float4 h4 = *(const float4*)(hrow + k + 4);
      float4 w0 = *(const float4*)(wrow + k);
      float4 w4 = *(const float4*)(wrow + k + 4);
      acc += h0.x * w0.x + h0.y * w0.y + h0.z * w0.z + h0.w * w0.w;
      acc += h4.x * w4.x + h4.y * w4.y + h4.z * w4.z + h4.w * w4.w;
    }
    acc += b2[lane];
    acc = acc > 0.f ? acc : 0.f;
    acc *= w3[lane];
  }
#pragma unroll
  for (int off = 32; off > 0; off >>= 1)
    acc += __shfl_down(acc, off);
  if (lane == 0)
    logits[wave] = 1.f / (1.f + expf(-(acc + b3[0])));
}

// ---- K3: ragged gather
__global__ __launch_bounds__(256)
void gather_kernel(const int* __restrict__ starts, const float* __restrict__ logits,
                   float* __restrict__ out) {
  const int i = blockIdx.x * 256 + threadIdx.x;
  if (i >= M_DIM) return;
  const int st = starts[i];
  int idx = st;
  if (idx < 0) idx = 0;
  if (idx > S_DIM - 1) idx = S_DIM - 1;
  out[i] = (st != 0) ? logits[((i >> 9) << 9) + idx] : 0.f;
}

extern "C" void kernel_launch(void* const* d_in, const int* in_sizes, int n_in,
                              void* d_out, int out_size, void* d_ws, size_t ws_size,
                              hipStream_t stream) {
  const float* hs = (const float*)d_in[0];
  const float* W1 = (const float*)d_in[1];
  const float* b1 = (const float*)d_in[2];
  const float* W2 = (const float*)d_in[3];
  const float* b2 = (const float*)d_in[4];
  const float* W3 = (const float*)d_in[5];
  const float* b3 = (const float*)d_in[6];
  const int* starts = (const int*)d_in[7];
  float* out = (float*)d_out;
  char* ws = (char*)d_ws;

  const size_t A_BYTES   = (size_t)M_DIM * K_DIM * 2;         // 805,306,368
  const size_t W1T_BYTES = (size_t)NP * K_DIM * 2;            //  50,331,648
  const size_t H1_BYTES  = (size_t)M_DIM * NP * 4;            //  67,108,864
  const size_t W2T_BYTES = 40 * NP * 4;
  const size_t B1P_BYTES = NP * 4;

  unsigned short* a    = (unsigned short*)ws;
  unsigned short* w1t  = (unsigned short*)(ws + A_BYTES);
  float* h1            = (float*)(ws + A_BYTES + W1T_BYTES);
  float* w2t           = (float*)(ws + A_BYTES + W1T_BYTES + H1_BYTES);
  float* b1p           = (float*)(ws + A_BYTES + W1T_BYTES + H1_BYTES + W2T_BYTES);
  float* logits        = (float*)(ws + A_BYTES + W1T_BYTES + H1_BYTES + W2T_BYTES + B1P_BYTES);

  hipFuncSetAttribute((const void*)gemm1_8ph_kernel,
                      hipFuncAttributeMaxDynamicSharedMemorySize, 131072);

  conv_a_kernel<<<2048, 256, 0, stream>>>(hs, starts, a);
  prep_w1t_kernel<<<dim3(16, 384), 256, 0, stream>>>(W1, w1t);
  prep_small_kernel<<<164, 256, 0, stream>>>(W2, b1, w2t, b1p);
  gemm1_8ph_kernel<<<256, 512, 131072, stream>>>(a, w1t, b1p, h1);
  layer23_kernel<<<4096, 256, 0, stream>>>(h1, w2t, b2, W3, b3, starts, logits);
  gather_kernel<<<64, 256, 0, stream>>>(starts, logits, out);
}

// Round 10
// 1284.533 us; speedup vs baseline: 1.1955x; 1.1955x over previous
//
#include <hip/hip_runtime.h>

typedef __attribute__((ext_vector_type(8))) short bf16x8;
typedef __attribute__((ext_vector_type(4))) float f32x4;

#define L_DIM 24
#define B_DIM 32
#define S_DIM 512
#define H_DIM 1024
#define M_DIM 16384      // B*S
#define K_DIM 24576      // L*H
#define N_REAL 900
#define NP 1024          // padded N

// round-to-nearest-even fp32 -> bf16
__device__ __forceinline__ short f2bf(float f) {
  unsigned u = __builtin_bit_cast(unsigned, f);
  u += 0x7FFFu + ((u >> 16) & 1u);
  return (short)(u >> 16);
}

// ---- C1: per-batch flags + local prefix of unique nonzero starts (sorted input)
__global__ __launch_bounds__(512)
void compact1_kernel(const int* __restrict__ starts, int* __restrict__ upos,
                     int* __restrict__ counts) {
  __shared__ int sc[512];
  const int b = blockIdx.x, t = threadIdx.x;
  const int v = starts[b * 512 + t];
  const int prev = (t > 0) ? starts[b * 512 + t - 1] : -1;
  const int flag = (v != 0 && v != prev) ? 1 : 0;
  sc[t] = flag;
  __syncthreads();
#pragma unroll
  for (int off = 1; off < 512; off <<= 1) {
    const int x = (t >= off) ? sc[t - off] : 0;
    __syncthreads();
    sc[t] += x;
    __syncthreads();
  }
  upos[b * 512 + t] = flag ? (sc[t] - 1) : -1;
  if (t == 511) counts[b] = sc[511];
}

// ---- C2: scan counts -> offsets, Mc, Mc_pad; pad idx tail with row 0
__global__ __launch_bounds__(256)
void compact2_kernel(const int* __restrict__ counts, int* __restrict__ offs,
                     int* __restrict__ meta, int* __restrict__ idx) {
  __shared__ int s0, s1;
  if (threadIdx.x == 0) {
    int acc = 0;
    for (int b = 0; b < 32; ++b) { offs[b] = acc; acc += counts[b]; }
    meta[0] = acc;                        // Mc
    meta[1] = (acc + 127) & ~127;         // Mc_pad (BM=128 multiple)
    s0 = acc; s1 = (acc + 127) & ~127;
  }
  __syncthreads();
  for (int j = s0 + threadIdx.x; j < s1; j += 256) idx[j] = 0;  // pad -> row 0
}

// ---- C3: scatter compact indices: idx[off_b + pos] = b*512 + value
__global__ __launch_bounds__(512)
void compact3_kernel(const int* __restrict__ starts, const int* __restrict__ upos,
                     const int* __restrict__ offs, int* __restrict__ idx) {
  const int b = blockIdx.x, t = threadIdx.x;
  const int p = upos[b * 512 + t];
  if (p >= 0) idx[offs[b] + p] = b * 512 + starts[b * 512 + t];
}

// ---- P0: compacted A: row j <- hs row idx[j], fp32->bf16, pre-swizzled by j&7:
// element (j,k) at k' = (k & ~63) + (((k>>3 & 7) ^ (j & 7)) * 8) + (k & 7)
__global__ __launch_bounds__(256)
void conv_a_kernel(const float* __restrict__ hs, const int* __restrict__ idx,
                   const int* __restrict__ meta, unsigned short* __restrict__ a) {
  const int mcp = meta[1];
  for (int j = blockIdx.x; j < mcp; j += gridDim.x) {
    const int m = idx[j];
    const int b = m >> 9, s = m & 511;
    const int j7 = j & 7;
    unsigned short* dstRow = a + (size_t)j * K_DIM;
#pragma unroll
    for (int i = 0; i < 12; ++i) {
      const int g = threadIdx.x + i * 256;        // granule (8 elems)
      const int l = g >> 7;
      const int h = (g & 127) * 8;
      const float* src = hs + (((size_t)l * B_DIM + b) * S_DIM + s) * H_DIM + h;
      float4 f0 = *(const float4*)src;
      float4 f1 = *(const float4*)(src + 4);
      bf16x8 p;
      p[0] = f2bf(f0.x); p[1] = f2bf(f0.y); p[2] = f2bf(f0.z); p[3] = f2bf(f0.w);
      p[4] = f2bf(f1.x); p[5] = f2bf(f1.y); p[6] = f2bf(f1.z); p[7] = f2bf(f1.w);
      const int slot = (g & 7) ^ j7;
      *(bf16x8*)(dstRow + (g & ~7) * 8 + slot * 8) = p;
    }
  }
}

// ---- P1: W1 [K][900] -> W1T bf16 [1024][K], zero-padded rows, swizzled (by n&7)
__global__ __launch_bounds__(256)
void prep_w1t_kernel(const float* __restrict__ w1, unsigned short* __restrict__ w1t) {
  __shared__ unsigned short t[64][72];
  const int n0 = blockIdx.x * 64;
  const int k0 = blockIdx.y * 64;
  const int tid = threadIdx.x;
  {
    const int nl = tid & 63;
    const int n = n0 + nl;
#pragma unroll
    for (int p = 0; p < 16; ++p) {
      const int kl = p * 4 + (tid >> 6);
      float v = (n < N_REAL) ? w1[(size_t)(k0 + kl) * N_REAL + n] : 0.f;
      t[nl][kl] = (unsigned short)f2bf(v);
    }
  }
  __syncthreads();
  {
    const int kl = tid & 63;
#pragma unroll
    for (int p = 0; p < 16; ++p) {
      const int nl2 = p * 4 + (tid >> 6);
      const int n = n0 + nl2;
      const int slot = ((kl >> 3) ^ (n & 7)) & 7;
      w1t[(size_t)n * K_DIM + k0 + slot * 8 + (kl & 7)] = t[nl2][kl];
    }
  }
}

// ---- P2: W2T fp32 [40][1024] (transposed, padded) + b1 padded [1024]
__global__ __launch_bounds__(256)
void prep_small_kernel(const float* __restrict__ w2, const float* __restrict__ b1,
                       float* __restrict__ w2t, float* __restrict__ b1p) {
  const int i = blockIdx.x * 256 + threadIdx.x;
  if (i < 40 * NP) {
    const int j = i >> 10, k = i & (NP - 1);
    w2t[i] = (k < N_REAL) ? w2[(size_t)k * 40 + j] : 0.f;
  }
  const int t2 = i - 40 * NP;
  if (t2 >= 0 && t2 < NP)
    b1p[t2] = (t2 < N_REAL) ? b1[t2] : 0.f;
}

// =====================================================================
// G1: h1 = relu(A @ W1T^T + b1). R3-proven structure: 128x128 tile, BK=64,
// 4 waves, single-buffered 32KB LDS, gload_lds staging, plain syncthreads.
// __launch_bounds__(256,4): 4 waves/SIMD -> ~4 blocks/CU resident; the
// independent blocks overlap each other's barrier/vmcnt drains (m114).
// Grid 1024 worst-case; blocks with m-panel >= Mc_pad exit immediately.
// XCD mapping: xcd c = hw&7 owns m-panels {c, c+8, ...} x all 8 n-blocks
// (A panel's 8 consumers share one XCD's L2; actives spread evenly).
// =====================================================================
__global__ __launch_bounds__(256, 4)
void gemm1_bf16_kernel(const unsigned short* __restrict__ a,
                       const unsigned short* __restrict__ w1t,
                       const float* __restrict__ b1p,
                       const int* __restrict__ meta,
                       float* __restrict__ h1) {
  __shared__ __align__(16) unsigned short Ab[128 * 64];   // 16 KiB
  __shared__ __align__(16) unsigned short Bb[128 * 64];   // 16 KiB

  const int mcp = meta[1];
  const int hw = blockIdx.x;
  const int c = hw & 7;               // XCD
  const int r = hw >> 3;              // 0..127
  const int mb = (r >> 3) * 8 + c;    // 0..127, round-robin over XCDs
  const int nb = r & 7;
  const int m0 = mb * 128;
  if (m0 >= mcp) return;
  const int n0 = nb * 128;

  const int tid = threadIdx.x;
  const int lane = tid & 63;
  const int wid = tid >> 6;
  const int wr = wid >> 1;     // 0..1 (64-row band)
  const int wc = wid & 1;      // 0..1 (64-col band)
  const int r15 = lane & 15;
  const int hi4 = lane >> 4;   // 0..3

  f32x4 acc[4][4] = {};

  const unsigned short* abase = a + (size_t)m0 * K_DIM;
  const unsigned short* bbase = w1t + (size_t)n0 * K_DIM;
  const int srow = lane >> 3;   // row within 8-row chunk
  const int sg = lane & 7;      // 16B granule within 128B row

  for (int k0 = 0; k0 < K_DIM; k0 += 64) {
    // stage A and B tiles: 16 chunks of 1 KiB each, 4 per wave
#pragma unroll
    for (int i = 0; i < 4; ++i) {
      const int ch = wid * 4 + i;
      const int row = ch * 8 + srow;
      __builtin_amdgcn_global_load_lds(
          (const __attribute__((address_space(1))) void*)(abase + (size_t)row * K_DIM + k0 + sg * 8),
          (__attribute__((address_space(3))) void*)((char*)Ab + ch * 1024),
          16, 0, 0);
      __builtin_amdgcn_global_load_lds(
          (const __attribute__((address_space(1))) void*)(bbase + (size_t)row * K_DIM + k0 + sg * 8),
          (__attribute__((address_space(3))) void*)((char*)Bb + ch * 1024),
          16, 0, 0);
    }
    __syncthreads();

#pragma unroll
    for (int kk = 0; kk < 2; ++kk) {
      bf16x8 av[4], bv[4];
#pragma unroll
      for (int mi = 0; mi < 4; ++mi) {
        const int row = wr * 64 + mi * 16 + r15;
        const int s = (kk * 4 + hi4) ^ (row & 7);
        av[mi] = *(const bf16x8*)((const char*)Ab + row * 128 + s * 16);
      }
#pragma unroll
      for (int ni = 0; ni < 4; ++ni) {
        const int row = wc * 64 + ni * 16 + r15;
        const int s = (kk * 4 + hi4) ^ (row & 7);
        bv[ni] = *(const bf16x8*)((const char*)Bb + row * 128 + s * 16);
      }
#pragma unroll
      for (int mi = 0; mi < 4; ++mi)
#pragma unroll
        for (int ni = 0; ni < 4; ++ni)
          acc[mi][ni] = __builtin_amdgcn_mfma_f32_16x16x32_bf16(av[mi], bv[ni], acc[mi][ni], 0, 0, 0);
    }
    __syncthreads();
  }

  // epilogue: relu(acc + b1); C/D: col = lane&15, row = (lane>>4)*4 + r
#pragma unroll
  for (int mi = 0; mi < 4; ++mi) {
#pragma unroll
    for (int ni = 0; ni < 4; ++ni) {
      const int n = n0 + wc * 64 + ni * 16 + r15;
      const float bias = b1p[n];
#pragma unroll
      for (int rr = 0; rr < 4; ++rr) {
        const int m = m0 + wr * 64 + mi * 16 + hi4 * 4 + rr;
        const float v = acc[mi][ni][rr] + bias;
        h1[(size_t)m * NP + n] = v > 0.f ? v : 0.f;
      }
    }
  }
}

// ---- K2: logits = sigmoid(relu(h1 @ W2 + b2) @ W3 + b3), one wave per
//          COMPACT row j; writes logits at the original position idx[j].
__global__ __launch_bounds__(256)
void layer23_kernel(const float* __restrict__ h1, const float* __restrict__ w2t,
                    const float* __restrict__ b2, const float* __restrict__ w3,
                    const float* __restrict__ b3, const int* __restrict__ idx,
                    const int* __restrict__ meta, float* __restrict__ logits) {
  const int j = (blockIdx.x * 256 + threadIdx.x) >> 6;
  if (j >= meta[0]) return;
  const int lane = threadIdx.x & 63;
  const float* hrow = h1 + (size_t)j * NP;
  float acc = 0.f;
  if (lane < 40) {
    const float* wrow = w2t + lane * NP;
    for (int k = 0; k < NP; k += 8) {
      float4 h0 = *(const float4*)(hrow + k);
      float4 h4 = *(const float4*)(hrow + k + 4);
      float4 w0 = *(const float4*)(wrow + k);
      float4 w4 = *(const float4*)(wrow + k + 4);
      acc += h0.x * w0.x + h0.y * w0.y + h0.z * w0.z + h0.w * w0.w;
      acc += h4.x * w4.x + h4.y * w4.y + h4.z * w4.z + h4.w * w4.w;
    }
    acc += b2[lane];
    acc = acc > 0.f ? acc : 0.f;
    acc *= w3[lane];
  }
#pragma unroll
  for (int off = 32; off > 0; off >>= 1)
    acc += __shfl_down(acc, off);
  if (lane == 0)
    logits[idx[j]] = 1.f / (1.f + expf(-(acc + b3[0])));
}

// ---- K3: ragged gather
__global__ __launch_bounds__(256)
void gather_kernel(const int* __restrict__ starts, const float* __restrict__ logits,
                   float* __restrict__ out) {
  const int i = blockIdx.x * 256 + threadIdx.x;
  if (i >= M_DIM) return;
  const int st = starts[i];
  int idx = st;
  if (idx < 0) idx = 0;
  if (idx > S_DIM - 1) idx = S_DIM - 1;
  out[i] = (st != 0) ? logits[((i >> 9) << 9) + idx] : 0.f;
}

extern "C" void kernel_launch(void* const* d_in, const int* in_sizes, int n_in,
                              void* d_out, int out_size, void* d_ws, size_t ws_size,
                              hipStream_t stream) {
  const float* hs = (const float*)d_in[0];
  const float* W1 = (const float*)d_in[1];
  const float* b1 = (const float*)d_in[2];
  const float* W2 = (const float*)d_in[3];
  const float* b2 = (const float*)d_in[4];
  const float* W3 = (const float*)d_in[5];
  const float* b3 = (const float*)d_in[6];
  const int* starts = (const int*)d_in[7];
  float* out = (float*)d_out;
  char* ws = (char*)d_ws;

  const size_t A_BYTES   = (size_t)M_DIM * K_DIM * 2;         // 805,306,368
  const size_t W1T_BYTES = (size_t)NP * K_DIM * 2;            //  50,331,648
  const size_t H1_BYTES  = (size_t)M_DIM * NP * 4;            //  67,108,864
  const size_t W2T_BYTES = 40 * NP * 4;                       //     163,840
  const size_t B1P_BYTES = NP * 4;                            //       4,096
  const size_t LG_BYTES  = M_DIM * 4;                         //      65,536

  unsigned short* a    = (unsigned short*)ws;
  unsigned short* w1t  = (unsigned short*)(ws + A_BYTES);
  char* h1c            = ws + A_BYTES + W1T_BYTES;
  float* h1            = (float*)h1c;
  float* w2t           = (float*)(ws + A_BYTES + W1T_BYTES + H1_BYTES);
  float* b1p           = (float*)(ws + A_BYTES + W1T_BYTES + H1_BYTES + W2T_BYTES);
  float* logits        = (float*)(ws + A_BYTES + W1T_BYTES + H1_BYTES + W2T_BYTES + B1P_BYTES);
  int* idx             = (int*)(ws + A_BYTES + W1T_BYTES + H1_BYTES + W2T_BYTES + B1P_BYTES + LG_BYTES);
  int* meta            = (int*)(ws + A_BYTES + W1T_BYTES + H1_BYTES + W2T_BYTES + B1P_BYTES + LG_BYTES + 65536);
  // transient compaction scratch lives inside h1 (h1 is written only later)
  int* upos            = (int*)h1c;                 // 64 KiB
  int* counts          = (int*)(h1c + 65536);       // 128 B
  int* offs            = (int*)(h1c + 65536 + 128); // 128 B

  compact1_kernel<<<32, 512, 0, stream>>>(starts, upos, counts);
  compact2_kernel<<<1, 256, 0, stream>>>(counts, offs, meta, idx);
  compact3_kernel<<<32, 512, 0, stream>>>(starts, upos, offs, idx);
  conv_a_kernel<<<2048, 256, 0, stream>>>(hs, idx, meta, a);
  prep_w1t_kernel<<<dim3(16, 384), 256, 0, stream>>>(W1, w1t);
  prep_small_kernel<<<164, 256, 0, stream>>>(W2, b1, w2t, b1p);
  gemm1_bf16_kernel<<<1024, 256, 0, stream>>>(a, w1t, b1p, meta, h1);
  layer23_kernel<<<4096, 256, 0, stream>>>(h1, w2t, b2, W3, b3, idx, meta, logits);
  gather_kernel<<<64, 256, 0, stream>>>(starts, logits, out);
}

// Round 11
// 1218.199 us; speedup vs baseline: 1.2606x; 1.0545x over previous
//
#include <hip/hip_runtime.h>

typedef __attribute__((ext_vector_type(8))) short bf16x8;
typedef __attribute__((ext_vector_type(4))) float f32x4;

#define L_DIM 24
#define B_DIM 32
#define S_DIM 512
#define H_DIM 1024
#define M_DIM 16384      // B*S
#define K_DIM 24576      // L*H
#define N_REAL 900
#define NP 1024          // padded N

// round-to-nearest-even fp32 -> bf16
__device__ __forceinline__ short f2bf(float f) {
  unsigned u = __builtin_bit_cast(unsigned, f);
  u += 0x7FFFu + ((u >> 16) & 1u);
  return (short)(u >> 16);
}

// ---- C1: per-batch flags + local prefix of unique nonzero starts (sorted input)
__global__ __launch_bounds__(512)
void compact1_kernel(const int* __restrict__ starts, int* __restrict__ upos,
                     int* __restrict__ counts) {
  __shared__ int sc[512];
  const int b = blockIdx.x, t = threadIdx.x;
  const int v = starts[b * 512 + t];
  const int prev = (t > 0) ? starts[b * 512 + t - 1] : -1;
  const int flag = (v != 0 && v != prev) ? 1 : 0;
  sc[t] = flag;
  __syncthreads();
#pragma unroll
  for (int off = 1; off < 512; off <<= 1) {
    const int x = (t >= off) ? sc[t - off] : 0;
    __syncthreads();
    sc[t] += x;
    __syncthreads();
  }
  upos[b * 512 + t] = flag ? (sc[t] - 1) : -1;
  if (t == 511) counts[b] = sc[511];
}

// ---- C2: scan counts -> offsets, Mc, Mc_pad (256-mult); pad idx tail with row 0
__global__ __launch_bounds__(256)
void compact2_kernel(const int* __restrict__ counts, int* __restrict__ offs,
                     int* __restrict__ meta, int* __restrict__ idx) {
  __shared__ int s0, s1;
  if (threadIdx.x == 0) {
    int acc = 0;
    for (int b = 0; b < 32; ++b) { offs[b] = acc; acc += counts[b]; }
    meta[0] = acc;                        // Mc
    meta[1] = (acc + 255) & ~255;         // Mc_pad (BM=256 multiple)
    s0 = acc; s1 = (acc + 255) & ~255;
  }
  __syncthreads();
  for (int j = s0 + threadIdx.x; j < s1; j += 256) idx[j] = 0;  // pad -> row 0
}

// ---- C3: scatter compact indices: idx[off_b + pos] = b*512 + value
__global__ __launch_bounds__(512)
void compact3_kernel(const int* __restrict__ starts, const int* __restrict__ upos,
                     const int* __restrict__ offs, int* __restrict__ idx) {
  const int b = blockIdx.x, t = threadIdx.x;
  const int p = upos[b * 512 + t];
  if (p >= 0) idx[offs[b] + p] = b * 512 + starts[b * 512 + t];
}

// ---- P0: compacted A: row j <- hs row idx[j], fp32->bf16, pre-swizzled by j&7:
// element (j,k) at k' = (k & ~63) + (((k>>3 & 7) ^ (j & 7)) * 8) + (k & 7)
__global__ __launch_bounds__(256)
void conv_a_kernel(const float* __restrict__ hs, const int* __restrict__ idx,
                   const int* __restrict__ meta, unsigned short* __restrict__ a) {
  const int mcp = meta[1];
  for (int j = blockIdx.x; j < mcp; j += gridDim.x) {
    const int m = idx[j];
    const int b = m >> 9, s = m & 511;
    const int j7 = j & 7;
    unsigned short* dstRow = a + (size_t)j * K_DIM;
#pragma unroll
    for (int i = 0; i < 12; ++i) {
      const int g = threadIdx.x + i * 256;        // granule (8 elems)
      const int l = g >> 7;
      const int h = (g & 127) * 8;
      const float* src = hs + (((size_t)l * B_DIM + b) * S_DIM + s) * H_DIM + h;
      float4 f0 = *(const float4*)src;
      float4 f1 = *(const float4*)(src + 4);
      bf16x8 p;
      p[0] = f2bf(f0.x); p[1] = f2bf(f0.y); p[2] = f2bf(f0.z); p[3] = f2bf(f0.w);
      p[4] = f2bf(f1.x); p[5] = f2bf(f1.y); p[6] = f2bf(f1.z); p[7] = f2bf(f1.w);
      const int slot = (g & 7) ^ j7;
      *(bf16x8*)(dstRow + (g & ~7) * 8 + slot * 8) = p;
    }
  }
}

// ---- P1: W1 [K][900] -> W1T bf16 [1024][K], zero-padded rows, swizzled (by n&7)
__global__ __launch_bounds__(256)
void prep_w1t_kernel(const float* __restrict__ w1, unsigned short* __restrict__ w1t) {
  __shared__ unsigned short t[64][72];
  const int n0 = blockIdx.x * 64;
  const int k0 = blockIdx.y * 64;
  const int tid = threadIdx.x;
  {
    const int nl = tid & 63;
    const int n = n0 + nl;
#pragma unroll
    for (int p = 0; p < 16; ++p) {
      const int kl = p * 4 + (tid >> 6);
      float v = (n < N_REAL) ? w1[(size_t)(k0 + kl) * N_REAL + n] : 0.f;
      t[nl][kl] = (unsigned short)f2bf(v);
    }
  }
  __syncthreads();
  {
    const int kl = tid & 63;
#pragma unroll
    for (int p = 0; p < 16; ++p) {
      const int nl2 = p * 4 + (tid >> 6);
      const int n = n0 + nl2;
      const int slot = ((kl >> 3) ^ (n & 7)) & 7;
      w1t[(size_t)n * K_DIM + k0 + slot * 8 + (kl & 7)] = t[nl2][kl];
    }
  }
}

// ---- P2: W2T fp32 [40][1024] (transposed, padded) + b1 padded [1024]
__global__ __launch_bounds__(256)
void prep_small_kernel(const float* __restrict__ w2, const float* __restrict__ b1,
                       float* __restrict__ w2t, float* __restrict__ b1p) {
  const int i = blockIdx.x * 256 + threadIdx.x;
  if (i < 40 * NP) {
    const int j = i >> 10, k = i & (NP - 1);
    w2t[i] = (k < N_REAL) ? w2[(size_t)k * 40 + j] : 0.f;
  }
  const int t2 = i - 40 * NP;
  if (t2 >= 0 && t2 < NP)
    b1p[t2] = (t2 < N_REAL) ? b1[t2] : 0.f;
}

// =====================================================================
// G1: h1 = relu(A @ W1T^T + b1). 256x256, BK=64, 4-phase, m201 cadence.
// Wave->row remap makes phases read CONTIGUOUS halves: ph1 reads A rows
// 0-127 (half a) + B half a; ph2 B half b; ph3 A half b. Staging, one
// half per phase: ph1: A_b(t+1); ph2: B_b(t+1); ph3: B_a(t+2); ph4: A_a(t+2).
// Drains: end-ph4 vmcnt(8) lands A_a,B_a(t+1); end-ph1 vmcnt(6) lands
// A_b,B_b(t+1). Every half gets >=3 phases of HBM flight time.
// =====================================================================
#define SBAR() do { __builtin_amdgcn_sched_barrier(0); __builtin_amdgcn_s_barrier(); __builtin_amdgcn_sched_barrier(0); } while (0)
#define WAIT_LGKM0() do { asm volatile("s_waitcnt lgkmcnt(0)" ::: "memory"); __builtin_amdgcn_sched_barrier(0); } while (0)
#define VMWAIT(N) do { asm volatile("s_waitcnt vmcnt(" #N ")" ::: "memory"); __builtin_amdgcn_sched_barrier(0); } while (0)

// stage one 128-row half-tile (16 KiB): 2 x global_load_lds per thread
#define STAGE(DSTREG, GBASE, ROWBASE, HALF, TK) do {                                   \
  _Pragma("unroll")                                                                    \
  for (int _i = 0; _i < 2; ++_i) {                                                     \
    const int _ch = wid * 2 + _i;                                                      \
    const int _row = (HALF) * 128 + _ch * 8 + (lane >> 3);                             \
    __builtin_amdgcn_global_load_lds(                                                  \
      (const __attribute__((address_space(1))) void*)((GBASE) +                        \
          (size_t)((ROWBASE) + _row) * K_DIM + (TK) * 64 + (lane & 7) * 8),            \
      (__attribute__((address_space(3))) void*)((DSTREG) + (HALF) * 16384 + _ch * 1024), \
      16, 0, 0);                                                                       \
  }                                                                                    \
} while (0)

// A fragment rows: half = MIBASE>>2 (0 or 1) -> rows half*128 + wr*64 + mi*16
#define LDA4(AV, MIBASE, ABUF) do {                                                    \
  _Pragma("unroll")                                                                    \
  for (int _mi = 0; _mi < 4; ++_mi) {                                                  \
    _Pragma("unroll")                                                                  \
    for (int _kk = 0; _kk < 2; ++_kk) {                                                \
      const int _r = ((MIBASE) >> 2) * 128 + wr * 64 + _mi * 16 + r15;                 \
      AV[_mi][_kk] = *(const bf16x8*)((ABUF) + _r * 128 + (((_kk)*4 + hi4) ^ (_r & 7)) * 16); \
    }                                                                                  \
  }                                                                                    \
} while (0)

// B fragment rows: half = NIBASE>>1 (0 or 1) -> rows half*128 + wc*32 + ni*16
#define LDB2(BV, NIBASE, BBUF) do {                                                    \
  _Pragma("unroll")                                                                    \
  for (int _ni = 0; _ni < 2; ++_ni) {                                                  \
    _Pragma("unroll")                                                                  \
    for (int _kk = 0; _kk < 2; ++_kk) {                                                \
      const int _r = ((NIBASE) >> 1) * 128 + wc * 32 + _ni * 16 + r15;                 \
      BV[_ni][_kk] = *(const bf16x8*)((BBUF) + _r * 128 + (((_kk)*4 + hi4) ^ (_r & 7)) * 16); \
    }                                                                                  \
  }                                                                                    \
} while (0)

#define MFMA_Q(AV, BV, MIBASE, NIBASE) do {                                            \
  _Pragma("unroll")                                                                    \
  for (int _mi = 0; _mi < 4; ++_mi)                                                    \
    _Pragma("unroll")                                                                  \
    for (int _ni = 0; _ni < 2; ++_ni)                                                  \
      _Pragma("unroll")                                                                \
      for (int _kk = 0; _kk < 2; ++_kk)                                                \
        acc[(MIBASE) + _mi][(NIBASE) + _ni] = __builtin_amdgcn_mfma_f32_16x16x32_bf16( \
            AV[_mi][_kk], BV[_ni][_kk], acc[(MIBASE) + _mi][(NIBASE) + _ni], 0, 0, 0); \
} while (0)

// one K-tile = 4 phases, quadrants (Aa,Ba)(Aa,Bb)(Ab,Bb)(Ab,Ba).
// S1: stage A_b(t+1) into ABN; S2: B_b(t+1) into BBN;
// S3: B_a(t+2) into BB; S4: A_a(t+2) into AB.
#define TILE_BODY(T, AB, BB, ABN, BBN, S1, S2, S3, S4, W1STMT, W4STMT) do {            \
  /* ---- phase 1 ---- */                                                              \
  LDA4(av, 0, (AB));                                                                   \
  LDB2(bv0, 0, (BB));                                                                  \
  if (S1) STAGE((ABN), a, m0, 1, (T) + 1);                                             \
  SBAR();                                                                              \
  WAIT_LGKM0();                                                                        \
  __builtin_amdgcn_s_setprio(1);                                                       \
  MFMA_Q(av, bv0, 0, 0);                                                               \
  __builtin_amdgcn_s_setprio(0);                                                       \
  W1STMT;                                                                              \
  SBAR();                                                                              \
  /* ---- phase 2 ---- */                                                              \
  LDB2(bv1, 2, (BB));                                                                  \
  if (S2) STAGE((BBN), w1t, n0, 1, (T) + 1);                                           \
  SBAR();                                                                              \
  WAIT_LGKM0();                                                                        \
  __builtin_amdgcn_s_setprio(1);                                                       \
  MFMA_Q(av, bv1, 0, 2);                                                               \
  __builtin_amdgcn_s_setprio(0);                                                       \
  SBAR();                                                                              \
  /* ---- phase 3 ---- */                                                              \
  LDA4(av, 4, (AB));                                                                   \
  if (S3) STAGE((BB), w1t, n0, 0, (T) + 2);                                            \
  SBAR();                                                                              \
  WAIT_LGKM0();                                                                        \
  __builtin_amdgcn_s_setprio(1);                                                       \
  MFMA_Q(av, bv1, 4, 2);                                                               \
  __builtin_amdgcn_s_setprio(0);                                                       \
  SBAR();                                                                              \
  /* ---- phase 4 ---- */                                                              \
  if (S4) STAGE((AB), a, m0, 0, (T) + 2);                                              \
  SBAR();                                                                              \
  WAIT_LGKM0();                                                                        \
  __builtin_amdgcn_s_setprio(1);                                                       \
  MFMA_Q(av, bv0, 4, 0);                                                               \
  __builtin_amdgcn_s_setprio(0);                                                       \
  W4STMT;                                                                              \
  SBAR();                                                                              \
} while (0)

__global__ __launch_bounds__(512, 2)
void gemm1_8ph_kernel(const unsigned short* __restrict__ a,
                      const unsigned short* __restrict__ w1t,
                      const float* __restrict__ b1p,
                      const int* __restrict__ meta,
                      float* __restrict__ h1) {
  const int mcp = meta[1];

  // XCD mapping: panel mb's 4 n-blocks share XCD c = mb&7
  const int hw = blockIdx.x;
  const int c = hw & 7;
  const int r = hw >> 3;              // 0..31
  const int mb = (r >> 2) * 8 + c;    // 0..63
  const int nb = r & 3;
  const int m0 = mb * 256;
  if (m0 >= mcp) return;
  const int n0 = nb * 256;

  extern __shared__ char L[];   // 128 KiB: A0|B0|A1|B1, 32 KiB each
  char* const Ab0 = L;
  char* const Bb0 = L + 32768;
  char* const Ab1 = L + 65536;
  char* const Bb1 = L + 65536 + 32768;

  const int tid = threadIdx.x;
  const int lane = tid & 63;
  const int wid = tid >> 6;          // 0..7
  const int wr = wid >> 2;           // 0..1 (64-row band within each 128-half)
  const int wc = wid & 3;            // 0..3 (32-col band within each 128-half)
  const int r15 = lane & 15;
  const int hi4 = lane >> 4;         // 0..3

  f32x4 acc[8][4] = {};
  bf16x8 av[4][2], bv0[2][2], bv1[2][2];

  // prologue in steady queue order: [Ba(0), Aa(0), Ab(0), Bb(0), Ba(1), Aa(1)]
  STAGE(Bb0, w1t, n0, 0, 0);
  STAGE(Ab0, a, m0, 0, 0);
  STAGE(Ab0, a, m0, 1, 0);
  STAGE(Bb0, w1t, n0, 1, 0);
  STAGE(Bb1, w1t, n0, 0, 1);
  STAGE(Ab1, a, m0, 0, 1);
  VMWAIT(8);     // land Ba(0), Aa(0); keep 4 halves in flight (steady state)
  SBAR();

  for (int kt = 0; kt < 191; ++kt) {
    const int t = 2 * kt;
    TILE_BODY(t,     Ab0, Bb0, Ab1, Bb1, 1, 1, 1, 1, VMWAIT(6), VMWAIT(8));
    TILE_BODY(t + 1, Ab1, Bb1, Ab0, Bb0, 1, 1, 1, 1, VMWAIT(6), VMWAIT(8));
  }
  // tail: 382 stages only A_b/B_b(383); full drain at its ph4. 383 computes.
  TILE_BODY(382, Ab0, Bb0, Ab1, Bb1, 1, 1, 0, 0, VMWAIT(6), VMWAIT(0));
  TILE_BODY(383, Ab1, Bb1, Ab0, Bb0, 0, 0, 0, 0, (void)0, (void)0);

  // epilogue: relu(acc + b1); C/D: col = lane&15, row = (lane>>4)*4 + r
#pragma unroll
  for (int mi = 0; mi < 8; ++mi) {
#pragma unroll
    for (int ni = 0; ni < 4; ++ni) {
      const int n = n0 + (ni >> 1) * 128 + wc * 32 + (ni & 1) * 16 + r15;
      const float bias = b1p[n];
#pragma unroll
      for (int rr = 0; rr < 4; ++rr) {
        const int m = m0 + (mi >> 2) * 128 + wr * 64 + (mi & 3) * 16 + hi4 * 4 + rr;
        const float v = acc[mi][ni][rr] + bias;
        h1[(size_t)m * NP + n] = v > 0.f ? v : 0.f;
      }
    }
  }
}

// ---- K2: logits = sigmoid(relu(h1 @ W2 + b2) @ W3 + b3), one wave per
//          COMPACT row j; writes logits at the original position idx[j].
__global__ __launch_bounds__(256)
void layer23_kernel(const float* __restrict__ h1, const float* __restrict__ w2t,
                    const float* __restrict__ b2, const float* __restrict__ w3,
                    const float* __restrict__ b3, const int* __restrict__ idx,
                    const int* __restrict__ meta, float* __restrict__ logits) {
  const int j = (blockIdx.x * 256 + threadIdx.x) >> 6;
  if (j >= meta[0]) return;
  const int lane = threadIdx.x & 63;
  const float* hrow = h1 + (size_t)j * NP;
  float acc = 0.f;
  if (lane < 40) {
    const float* wrow = w2t + lane * NP;
    for (int k = 0; k < NP; k += 8) {
      float4 h0 = *(const float4*)(hrow + k);
      float4 h4 = *(const float4*)(hrow + k + 4);
      float4 w0 = *(const float4*)(wrow + k);
      float4 w4 = *(const float4*)(wrow + k + 4);
      acc += h0.x * w0.x + h0.y * w0.y + h0.z * w0.z + h0.w * w0.w;
      acc += h4.x * w4.x + h4.y * w4.y + h4.z * w4.z + h4.w * w4.w;
    }
    acc += b2[lane];
    acc = acc > 0.f ? acc : 0.f;
    acc *= w3[lane];
  }
#pragma unroll
  for (int off = 32; off > 0; off >>= 1)
    acc += __shfl_down(acc, off);
  if (lane == 0)
    logits[idx[j]] = 1.f / (1.f + expf(-(acc + b3[0])));
}

// ---- K3: ragged gather
__global__ __launch_bounds__(256)
void gather_kernel(const int* __restrict__ starts, const float* __restrict__ logits,
                   float* __restrict__ out) {
  const int i = blockIdx.x * 256 + threadIdx.x;
  if (i >= M_DIM) return;
  const int st = starts[i];
  int idx = st;
  if (idx < 0) idx = 0;
  if (idx > S_DIM - 1) idx = S_DIM - 1;
  out[i] = (st != 0) ? logits[((i >> 9) << 9) + idx] : 0.f;
}

extern "C" void kernel_launch(void* const* d_in, const int* in_sizes, int n_in,
                              void* d_out, int out_size, void* d_ws, size_t ws_size,
                              hipStream_t stream) {
  const float* hs = (const float*)d_in[0];
  const float* W1 = (const float*)d_in[1];
  const float* b1 = (const float*)d_in[2];
  const float* W2 = (const float*)d_in[3];
  const float* b2 = (const float*)d_in[4];
  const float* W3 = (const float*)d_in[5];
  const float* b3 = (const float*)d_in[6];
  const int* starts = (const int*)d_in[7];
  float* out = (float*)d_out;
  char* ws = (char*)d_ws;

  const size_t A_BYTES   = (size_t)M_DIM * K_DIM * 2;         // 805,306,368
  const size_t W1T_BYTES = (size_t)NP * K_DIM * 2;            //  50,331,648
  const size_t H1_BYTES  = (size_t)M_DIM * NP * 4;            //  67,108,864
  const size_t W2T_BYTES = 40 * NP * 4;                       //     163,840
  const size_t B1P_BYTES = NP * 4;                            //       4,096
  const size_t LG_BYTES  = M_DIM * 4;                         //      65,536

  unsigned short* a    = (unsigned short*)ws;
  unsigned short* w1t  = (unsigned short*)(ws + A_BYTES);
  char* h1c            = ws + A_BYTES + W1T_BYTES;
  float* h1            = (float*)h1c;
  float* w2t           = (float*)(ws + A_BYTES + W1T_BYTES + H1_BYTES);
  float* b1p           = (float*)(ws + A_BYTES + W1T_BYTES + H1_BYTES + W2T_BYTES);
  float* logits        = (float*)(ws + A_BYTES + W1T_BYTES + H1_BYTES + W2T_BYTES + B1P_BYTES);
  int* idx             = (int*)(ws + A_BYTES + W1T_BYTES + H1_BYTES + W2T_BYTES + B1P_BYTES + LG_BYTES);
  int* meta            = (int*)(ws + A_BYTES + W1T_BYTES + H1_BYTES + W2T_BYTES + B1P_BYTES + LG_BYTES + 65536);
  // transient compaction scratch lives inside h1 (h1 is written only later)
  int* upos            = (int*)h1c;                 // 64 KiB
  int* counts          = (int*)(h1c + 65536);       // 128 B
  int* offs            = (int*)(h1c + 65536 + 128); // 128 B

  hipFuncSetAttribute((const void*)gemm1_8ph_kernel,
                      hipFuncAttributeMaxDynamicSharedMemorySize, 131072);

  compact1_kernel<<<32, 512, 0, stream>>>(starts, upos, counts);
  compact2_kernel<<<1, 256, 0, stream>>>(counts, offs, meta, idx);
  compact3_kernel<<<32, 512, 0, stream>>>(starts, upos, offs, idx);
  conv_a_kernel<<<2048, 256, 0, stream>>>(hs, idx, meta, a);
  prep_w1t_kernel<<<dim3(16, 384), 256, 0, stream>>>(W1, w1t);
  prep_small_kernel<<<164, 256, 0, stream>>>(W2, b1, w2t, b1p);
  gemm1_8ph_kernel<<<256, 512, 131072, stream>>>(a, w1t, b1p, meta, h1);
  layer23_kernel<<<4096, 256, 0, stream>>>(h1, w2t, b2, W3, b3, idx, meta, logits);
  gather_kernel<<<64, 256, 0, stream>>>(starts, logits, out);
}